// Round 1
// baseline (11880.590 us; speedup 1.0000x reference)
//
#include <hip/hip_runtime.h>
#include <hip/hip_bf16.h>
#include <cstdio>

typedef __hip_bfloat16 bf16;

#define T_WIN 1993      // N_WINDOWS
#define NSER 512
#define NTIME 2048
#define HID 64
#define H4 256

__device__ __forceinline__ float sigmf(float x) { return 1.f/(1.f+__expf(-x)); }
__device__ __forceinline__ float tanhf_fast(float x) { return 1.f - 2.f/(__expf(2.f*x)+1.f); }

// ---------------- ES scan: 1 thread per series ----------------
__global__ void es_kernel(const float* __restrict__ y, const int* __restrict__ idxs,
                          const float* __restrict__ lev_sms, const float* __restrict__ seas_sms,
                          const float* __restrict__ init_seas,
                          float* __restrict__ levels, float* __restrict__ seas) {
  int s = blockIdx.x*blockDim.x + threadIdx.x;
  if (s >= NSER) return;
  int id = idxs[s];
  float ls = sigmf(lev_sms[id]);
  float ss = sigmf(seas_sms[id]);
  float buf[8];
  #pragma unroll
  for (int k=0;k<7;++k) buf[k] = __expf(init_seas[id*7+k]);
  buf[7] = buf[0];
  const float* yr = y + (size_t)s*NTIME;
  float* lr = levels + (size_t)s*NTIME;
  float* sr = seas + (size_t)s*NTIME;
  float lev = __fdividef(yr[0], buf[0]);
  lr[0] = lev;
  #pragma unroll
  for (int t=0;t<8;++t) sr[t] = buf[t];
  #pragma unroll 8
  for (int t=1;t<NTIME;++t) {
    float yt = yr[t];
    float st = buf[1];
    lev = ls*__fdividef(yt,st) + (1.f-ls)*lev;
    float ns = ss*__fdividef(yt,lev) + (1.f-ss)*st;
    #pragma unroll
    for (int k=0;k<7;++k) buf[k] = buf[k+1];
    buf[7] = ns;
    lr[t] = lev;
    if (t+7 < NTIME) sr[t+7] = ns;
  }
}

// ---------------- log(norm), log(levels) ----------------
__global__ void lnorm_kernel(const float* __restrict__ y, const float* __restrict__ seas,
                             const float* __restrict__ levels,
                             float* __restrict__ lnorm, float* __restrict__ llev) {
  int i = blockIdx.x*256 + threadIdx.x;
  lnorm[i] = __logf(__fdividef(y[i], seas[i]));
  llev[i]  = __logf(levels[i]);
}

// ---------------- windows: windows_y (out0) + RNN input xhat ----------------
__global__ void window_kernel(const float* __restrict__ lnorm, const float* __restrict__ llev,
                              const float* __restrict__ noise,
                              float* __restrict__ wy, bf16* __restrict__ xhat) {
  int idx = blockIdx.x*256 + threadIdx.x;   // (w*512 + s)*28 + k
  int k  = idx % 28;
  int rs = idx / 28;
  int s  = rs & 511;
  int w  = rs >> 9;
  float lv = llev[s*NTIME + 28 + w];
  const float* Ln = lnorm + s*NTIME;
  wy[idx]   = Ln[w+28+k] - lv;
  xhat[idx] = __float2bfloat16(Ln[w+k] - lv + 0.001f*noise[idx]);
}

// ---------------- dilated LSTM scan: 1 block (256 thr) per sequence ----------------
template<int D>
__global__ __launch_bounds__(256) void lstm_kernel(const bf16* __restrict__ x, bf16* __restrict__ hout,
            const float* __restrict__ Wih, const float* __restrict__ Whh,
            const float* __restrict__ bih, const float* __restrict__ bhh, int rate) {
  const int b = blockIdx.x & 511;
  const int j = blockIdx.x >> 9;      // residue class (dilation phase)
  const int i = threadIdx.x;          // gate-row 0..255
  const int u = i & 63;
  const int g = i >> 6;               // = wave id

  float wh[64];
  #pragma unroll
  for (int k=0;k<64;++k) wh[k] = Whh[i*64+k];
  float wx[D];
  #pragma unroll
  for (int d=0;d<D;++d) wx[d] = Wih[i*D+d];
  const float bias = bih[i] + bhh[i];

  __shared__ __align__(16) float hbuf[64];
  __shared__ float zbuf[4*68];              // stride 68: conflict-free
  __shared__ __align__(16) float xst[8][D]; // D*4 is multiple of 16

  float c = 0.f;
  if (i < 64) hbuf[i] = 0.f;
  __syncthreads();

  const int nsteps = (T_WIN - 1 - j)/rate + 1;   // #t with t=j+s*rate < T_WIN
  for (int s0 = 0; s0 < nsteps; s0 += 8) {
    const int nst = min(8, nsteps - s0);
    for (int e = i; e < 8*D; e += 256) {
      int m = e / D, d = e - m*D;
      float v = 0.f;
      if (m < nst) {
        int t = j + (s0+m)*rate;
        v = __bfloat162float(x[(size_t)t*(512*D) + b*D + d]);
      }
      xst[m][d] = v;
    }
    __syncthreads();
    for (int m = 0; m < nst; ++m) {
      const int t = j + (s0+m)*rate;
      float z0 = bias, z1 = 0.f, z2 = 0.f, z3 = 0.f;
      const float4* hp = (const float4*)hbuf;
      #pragma unroll
      for (int k=0;k<16;++k) {
        float4 hv = hp[k];
        z0 += wh[4*k+0]*hv.x; z1 += wh[4*k+1]*hv.y;
        z2 += wh[4*k+2]*hv.z; z3 += wh[4*k+3]*hv.w;
      }
      const float4* xp = (const float4*)(&xst[m][0]);
      #pragma unroll
      for (int d=0;d<D/4;++d) {
        float4 xv = xp[d];
        z0 += wx[4*d+0]*xv.x; z1 += wx[4*d+1]*xv.y;
        z2 += wx[4*d+2]*xv.z; z3 += wx[4*d+3]*xv.w;
      }
      zbuf[g*68+u] = (z0+z1)+(z2+z3);
      __syncthreads();
      if (i < 64) {
        float zi = zbuf[i], zf = zbuf[68+i], zg = zbuf[136+i], zo = zbuf[204+i];
        c = sigmf(zf)*c + sigmf(zi)*tanhf_fast(zg);
        float hh = sigmf(zo)*tanhf_fast(c);
        hbuf[i] = hh;
        hout[(size_t)t*(512*64) + b*64 + i] = __float2bfloat16(hh);
      }
      __syncthreads();
    }
  }
}

// ---------------- adapter: out1 = (h4+h2) @ adW.T + adb ----------------
__global__ __launch_bounds__(256) void adapter_kernel(const bf16* __restrict__ h4, const bf16* __restrict__ h2,
      const float* __restrict__ adW, const float* __restrict__ adb, float* __restrict__ out) {
  __shared__ __align__(16) float xrow[64*64];
  const int i = threadIdx.x;
  const int total = T_WIN*512;
  const int base = blockIdx.x * 64;
  for (int e = i; e < 64*64; e += 256) {
    int r = e >> 6;
    size_t gi = (size_t)(base + r)*64 + (e & 63);
    float v = 0.f;
    if (base + r < total) v = __bfloat162float(h4[gi]) + __bfloat162float(h2[gi]);
    xrow[e] = v;
  }
  const int o  = i & 31;   // output col (28 active)
  const int rg = i >> 5;   // 8 row-groups of 8 rows
  float w[64]; float bo = 0.f;
  if (o < 28) {
    #pragma unroll
    for (int uu=0;uu<64;++uu) w[uu] = adW[o*64+uu];
    bo = adb[o];
  }
  __syncthreads();
  if (o < 28) {
    #pragma unroll
    for (int rr=0; rr<8; ++rr) {
      int r = rg*8 + rr;
      if (base + r >= total) break;
      const float4* xp = (const float4*)(&xrow[r*64]);
      float a0 = bo, a1 = 0.f, a2 = 0.f, a3 = 0.f;
      #pragma unroll
      for (int q=0;q<16;++q) {
        float4 xv = xp[q];
        a0 += w[4*q+0]*xv.x; a1 += w[4*q+1]*xv.y;
        a2 += w[4*q+2]*xv.z; a3 += w[4*q+3]*xv.w;
      }
      out[(size_t)(base+r)*28 + o] = (a0+a1)+(a2+a3);
    }
  }
}

extern "C" void kernel_launch(void* const* d_in, const int* in_sizes, int n_in,
                              void* d_out, int out_size, void* d_ws, size_t ws_size,
                              hipStream_t stream) {
  const float* y         = (const float*)d_in[0];
  const int*   idxs      = (const int*)d_in[1];
  const float* noise     = (const float*)d_in[2];
  const float* lev_sms   = (const float*)d_in[3];
  const float* seas_sms  = (const float*)d_in[4];
  const float* init_seas = (const float*)d_in[5];
  const float* Wih0      = (const float*)d_in[6];
  const float* Wih_rest  = (const float*)d_in[7];
  const float* Whh_all   = (const float*)d_in[8];
  const float* bih_all   = (const float*)d_in[9];
  const float* bhh_all   = (const float*)d_in[10];
  const float* adW       = (const float*)d_in[11];
  const float* adb       = (const float*)d_in[12];

  const size_t NWIN28 = (size_t)T_WIN*512*28;   // 28,571,648
  const size_t NWIN64 = (size_t)T_WIN*512*64;   // 65,306,624
  float* out_wy   = (float*)d_out;
  float* out_yhat = out_wy + NWIN28;
  float* out_lev  = out_yhat + NWIN28;

  float* seas  = (float*)d_ws;            // 512*2048
  float* lnorm = seas  + (size_t)NSER*NTIME;
  float* llev  = lnorm + (size_t)NSER*NTIME;
  bf16* xhat = (bf16*)(llev + (size_t)NSER*NTIME);
  bf16* h1   = (bf16*)((char*)xhat + NWIN28*2);
  bf16* h2   = (bf16*)((char*)h1 + NWIN64*2);
  bf16* h4   = (bf16*)((char*)h2 + NWIN64*2);
  bf16* h3   = h1;  // reuse: h1 dead once layer2 starts

  size_t need = (size_t)3*NSER*NTIME*4 + NWIN28*2 + 3*NWIN64*2;
  if (ws_size < need) {
    fprintf(stderr, "kernel_launch: ws_size %zu < needed %zu\n", ws_size, need);
    return;
  }

  es_kernel<<<2,256,0,stream>>>(y, idxs, lev_sms, seas_sms, init_seas, out_lev, seas);
  lnorm_kernel<<<(NSER*NTIME)/256,256,0,stream>>>(y, seas, out_lev, lnorm, llev);
  window_kernel<<<NWIN28/256,256,0,stream>>>(lnorm, llev, noise, out_wy, xhat);

  lstm_kernel<28><<< 512,256,0,stream>>>(xhat, h1, Wih0,            Whh_all,          bih_all,       bhh_all,       1);
  lstm_kernel<64><<<1024,256,0,stream>>>(h1,   h2, Wih_rest,        Whh_all+  256*64, bih_all+  256, bhh_all+  256, 2);
  lstm_kernel<64><<<2048,256,0,stream>>>(h2,   h3, Wih_rest+256*64, Whh_all+2*256*64, bih_all+2*256, bhh_all+2*256, 4);
  lstm_kernel<64><<<4096,256,0,stream>>>(h3,   h4, Wih_rest+2*256*64, Whh_all+3*256*64, bih_all+3*256, bhh_all+3*256, 8);

  adapter_kernel<<<(T_WIN*512)/64,256,0,stream>>>(h4, h2, adW, adb, out_yhat);
}

// Round 2
// 5911.552 us; speedup vs baseline: 2.0097x; 2.0097x over previous
//
#include <hip/hip_runtime.h>
#include <hip/hip_bf16.h>
#include <cstdio>

typedef __hip_bfloat16 bf16;
typedef __attribute__((ext_vector_type(8))) short short8v;
typedef __attribute__((ext_vector_type(4))) float f32x4;

#define T_WIN 1993      // N_WINDOWS
#define NSER 512
#define NTIME 2048

__device__ __forceinline__ float sigmf(float x) { return __fdividef(1.f, 1.f + __expf(-x)); }
__device__ __forceinline__ float tanhf_fast(float x) { return 1.f - __fdividef(2.f, __expf(2.f*x) + 1.f); }
__device__ __forceinline__ ushort f2bfu(float f) {
  __hip_bfloat16 h = __float2bfloat16(f);
  return *reinterpret_cast<ushort*>(&h);
}

// ---------------- ES scan: 1 thread per series ----------------
__global__ void es_kernel(const float* __restrict__ y, const int* __restrict__ idxs,
                          const float* __restrict__ lev_sms, const float* __restrict__ seas_sms,
                          const float* __restrict__ init_seas,
                          float* __restrict__ levels, float* __restrict__ seas) {
  int s = blockIdx.x*blockDim.x + threadIdx.x;
  if (s >= NSER) return;
  int id = idxs[s];
  float ls = sigmf(lev_sms[id]);
  float ss = sigmf(seas_sms[id]);
  float buf[8];
  #pragma unroll
  for (int k=0;k<7;++k) buf[k] = __expf(init_seas[id*7+k]);
  buf[7] = buf[0];
  const float* yr = y + (size_t)s*NTIME;
  float* lr = levels + (size_t)s*NTIME;
  float* sr = seas + (size_t)s*NTIME;
  float lev = __fdividef(yr[0], buf[0]);
  lr[0] = lev;
  #pragma unroll
  for (int t=0;t<8;++t) sr[t] = buf[t];
  #pragma unroll 8
  for (int t=1;t<NTIME;++t) {
    float yt = yr[t];
    float st = buf[1];
    lev = ls*__fdividef(yt,st) + (1.f-ls)*lev;
    float ns = ss*__fdividef(yt,lev) + (1.f-ss)*st;
    #pragma unroll
    for (int k=0;k<7;++k) buf[k] = buf[k+1];
    buf[7] = ns;
    lr[t] = lev;
    if (t+7 < NTIME) sr[t+7] = ns;
  }
}

// ---------------- log(norm), log(levels) ----------------
__global__ void lnorm_kernel(const float* __restrict__ y, const float* __restrict__ seas,
                             const float* __restrict__ levels,
                             float* __restrict__ lnorm, float* __restrict__ llev) {
  int i = blockIdx.x*256 + threadIdx.x;
  lnorm[i] = __logf(__fdividef(y[i], seas[i]));
  llev[i]  = __logf(levels[i]);
}

// ---------------- windows: windows_y (out0) + RNN input xhat ----------------
__global__ void window_kernel(const float* __restrict__ lnorm, const float* __restrict__ llev,
                              const float* __restrict__ noise,
                              float* __restrict__ wy, ushort* __restrict__ xhat) {
  int idx = blockIdx.x*256 + threadIdx.x;   // (w*512 + s)*28 + k
  int k  = idx % 28;
  int rs = idx / 28;
  int s  = rs & 511;
  int w  = rs >> 9;
  float lv = llev[s*NTIME + 28 + w];
  const float* Ln = lnorm + s*NTIME;
  wy[idx]   = Ln[w+28+k] - lv;
  xhat[idx] = f2bfu(Ln[w+k] - lv + 0.001f*noise[idx]);
}

// ---------------- x tile staging (16 rows of D bf16 into padded LDS) -------
template<int D>
__device__ __forceinline__ void stage_x(const ushort* __restrict__ xin, ushort* dst,
                                        int t, int base, int i) {
  if (D == 64) {
    const int r = i >> 4, c4 = i & 15;     // 256 thr * 8B = 2KB
    ushort4 v = *reinterpret_cast<const ushort4*>(xin + ((size_t)t*512 + base + r)*64 + c4*4);
    *reinterpret_cast<ushort4*>(dst + r*72 + c4*4) = v;
  } else {
    if (i < 224) {                          // 224 thr * 4B
      const int r = i / 14, c2 = i % 14;
      ushort2 v = *reinterpret_cast<const ushort2*>(xin + ((size_t)t*512 + base + r)*28 + c2*2);
      *reinterpret_cast<ushort2*>(dst + r*40 + c2*2) = v;
    }
  }
}

// ---------------- MFMA dilated LSTM scan: 16 sequences per block -----------
// Wave w owns hidden units [16w,16w+16), all 4 gates (permuted weight rows).
// Z = [x_t | h] @ [Wih | Whh]^T via mfma_f32_16x16x32_bf16, M=16 batch.
template<int D>
__global__ __launch_bounds__(256, 1)
void lstm_mfma(const ushort* __restrict__ xin, ushort* __restrict__ hout,
               const float* __restrict__ Wih, const float* __restrict__ Whh,
               const float* __restrict__ bih, const float* __restrict__ bhh,
               const int rate) {
  constexpr int KX  = (D == 28) ? 32 : 64;   // padded x-K
  constexpr int KXS = KX / 32;               // x k-steps (1 or 2)
  constexpr int KST = KXS + 2;               // total k-steps (3 or 4)
  constexpr int XSU = (D == 28) ? 40 : 72;   // x LDS row stride in units

  __shared__ ushort xbuf[2][16*XSU];
  __shared__ ushort hbuf[2][16*72];

  const int i    = threadIdx.x;
  const int lane = i & 63;
  const int wid  = i >> 6;        // wave 0..3
  const int n15  = lane & 15;     // MFMA N index / unit-within-wave / batch row (A)
  const int kq   = lane >> 4;     // k-quarter
  const int j    = blockIdx.x >> 5;        // dilation phase
  const int base = (blockIdx.x & 31) * 16; // series group

  // ---- weight B-fragments (permuted rows: gate g, unit 16*wid+n15) ----
  short8v wfrag[4][KST];
  float bias[4];
  #pragma unroll
  for (int g = 0; g < 4; ++g) {
    const int R = g*64 + wid*16 + n15;
    bias[g] = bih[R] + bhh[R];
    #pragma unroll
    for (int kk = 0; kk < KST; ++kk) {
      #pragma unroll
      for (int jj = 0; jj < 8; ++jj) {
        const int k = kk*32 + kq*8 + jj;
        float v;
        if (k < KX) v = (k < D) ? Wih[R*D + k] : 0.f;
        else        v = Whh[R*64 + (k - KX)];
        wfrag[g][kk][jj] = (short)f2bfu(v);
      }
    }
  }

  // zero h state
  for (int e = i; e < 1024; e += 256) hbuf[0][(e>>6)*72 + (e&63)] = 0;
  if (D == 28) {  // zero x pad cols 28..31 in both buffers
    for (int e = i; e < 128; e += 256) {
      int b = e >> 6, m = (e>>2)&15, cc = e&3;
      xbuf[b][m*XSU + 28 + cc] = 0;
    }
  }
  const int nsteps = (T_WIN - 1 - j)/rate + 1;
  stage_x<D>(xin, xbuf[0], j, base, i);
  __syncthreads();

  float cc[4] = {0.f, 0.f, 0.f, 0.f};
  const int u = wid*16 + n15;

  for (int s = 0; s < nsteps; ++s) {
    const int p = s & 1;
    const int t = j + s*rate;
    // A-fragments: lane reads row m=n15, k-range kq*8..+8
    short8v afr[KST];
    #pragma unroll
    for (int kk = 0; kk < KXS; ++kk)
      afr[kk] = *reinterpret_cast<const short8v*>(&xbuf[p][n15*XSU + kk*32 + kq*8]);
    #pragma unroll
    for (int t2 = 0; t2 < 2; ++t2)
      afr[KXS+t2] = *reinterpret_cast<const short8v*>(&hbuf[p][n15*72 + t2*32 + kq*8]);
    // prefetch next x tile into the other buffer (overlaps MFMA+gates)
    if (s + 1 < nsteps) stage_x<D>(xin, xbuf[p^1], t + rate, base, i);
    // MFMA: acc[g] starts at bias (same for all batch rows)
    f32x4 acc[4];
    #pragma unroll
    for (int g = 0; g < 4; ++g) acc[g] = (f32x4){bias[g], bias[g], bias[g], bias[g]};
    #pragma unroll
    for (int kk = 0; kk < KST; ++kk) {
      #pragma unroll
      for (int g = 0; g < 4; ++g)
        acc[g] = __builtin_amdgcn_mfma_f32_16x16x32_bf16(afr[kk], wfrag[g][kk], acc[g], 0, 0, 0);
    }
    // gates: lane holds z_i,z_f,z_g,z_o for (batch m=kq*4+r, unit u) in reg r
    #pragma unroll
    for (int r = 0; r < 4; ++r) {
      const float zi = acc[0][r], zf = acc[1][r], zg = acc[2][r], zo = acc[3][r];
      const float si = sigmf(zi), sf = sigmf(zf), so = sigmf(zo);
      cc[r] = sf*cc[r] + si*tanhf_fast(zg);
      const float h = so*tanhf_fast(cc[r]);
      const ushort hu = f2bfu(h);
      const int m = kq*4 + r;
      hbuf[p^1][m*72 + u] = hu;
      hout[((size_t)t*512 + base + m)*64 + u] = hu;
    }
    __syncthreads();
  }
}

// ---------------- adapter: out1 = (h4+h2) @ adW.T + adb ----------------
__global__ __launch_bounds__(256) void adapter_kernel(const ushort* __restrict__ h4, const ushort* __restrict__ h2,
      const float* __restrict__ adW, const float* __restrict__ adb, float* __restrict__ out) {
  __shared__ __align__(16) float xrow[64*64];
  const int i = threadIdx.x;
  const int total = T_WIN*512;
  const int base = blockIdx.x * 64;
  for (int e = i; e < 64*64; e += 256) {
    int r = e >> 6;
    size_t gi = (size_t)(base + r)*64 + (e & 63);
    float v = 0.f;
    if (base + r < total) {
      __hip_bfloat16 a = *reinterpret_cast<const __hip_bfloat16*>(h4 + gi);
      __hip_bfloat16 b = *reinterpret_cast<const __hip_bfloat16*>(h2 + gi);
      v = __bfloat162float(a) + __bfloat162float(b);
    }
    xrow[e] = v;
  }
  const int o  = i & 31;
  const int rg = i >> 5;
  float w[64]; float bo = 0.f;
  if (o < 28) {
    #pragma unroll
    for (int uu=0;uu<64;++uu) w[uu] = adW[o*64+uu];
    bo = adb[o];
  }
  __syncthreads();
  if (o < 28) {
    #pragma unroll
    for (int rr=0; rr<8; ++rr) {
      int r = rg*8 + rr;
      if (base + r >= total) break;
      const float4* xp = (const float4*)(&xrow[r*64]);
      float a0 = bo, a1 = 0.f, a2 = 0.f, a3 = 0.f;
      #pragma unroll
      for (int q=0;q<16;++q) {
        float4 xv = xp[q];
        a0 += w[4*q+0]*xv.x; a1 += w[4*q+1]*xv.y;
        a2 += w[4*q+2]*xv.z; a3 += w[4*q+3]*xv.w;
      }
      out[(size_t)(base+r)*28 + o] = (a0+a1)+(a2+a3);
    }
  }
}

extern "C" void kernel_launch(void* const* d_in, const int* in_sizes, int n_in,
                              void* d_out, int out_size, void* d_ws, size_t ws_size,
                              hipStream_t stream) {
  const float* y         = (const float*)d_in[0];
  const int*   idxs      = (const int*)d_in[1];
  const float* noise     = (const float*)d_in[2];
  const float* lev_sms   = (const float*)d_in[3];
  const float* seas_sms  = (const float*)d_in[4];
  const float* init_seas = (const float*)d_in[5];
  const float* Wih0      = (const float*)d_in[6];
  const float* Wih_rest  = (const float*)d_in[7];
  const float* Whh_all   = (const float*)d_in[8];
  const float* bih_all   = (const float*)d_in[9];
  const float* bhh_all   = (const float*)d_in[10];
  const float* adW       = (const float*)d_in[11];
  const float* adb       = (const float*)d_in[12];

  const size_t NWIN28 = (size_t)T_WIN*512*28;
  const size_t NWIN64 = (size_t)T_WIN*512*64;
  float* out_wy   = (float*)d_out;
  float* out_yhat = out_wy + NWIN28;
  float* out_lev  = out_yhat + NWIN28;

  float* seas  = (float*)d_ws;
  float* lnorm = seas  + (size_t)NSER*NTIME;
  float* llev  = lnorm + (size_t)NSER*NTIME;
  ushort* xhat = (ushort*)(llev + (size_t)NSER*NTIME);
  ushort* h1   = (ushort*)((char*)xhat + NWIN28*2);
  ushort* h2   = (ushort*)((char*)h1 + NWIN64*2);
  ushort* h4   = (ushort*)((char*)h2 + NWIN64*2);
  ushort* h3   = h1;  // reuse: h1 dead once layer 3 starts

  size_t need = (size_t)3*NSER*NTIME*4 + NWIN28*2 + 3*NWIN64*2;
  if (ws_size < need) {
    fprintf(stderr, "kernel_launch: ws_size %zu < needed %zu\n", ws_size, need);
    return;
  }

  es_kernel<<<2,256,0,stream>>>(y, idxs, lev_sms, seas_sms, init_seas, out_lev, seas);
  lnorm_kernel<<<(NSER*NTIME)/256,256,0,stream>>>(y, seas, out_lev, lnorm, llev);
  window_kernel<<<NWIN28/256,256,0,stream>>>(lnorm, llev, noise, out_wy, xhat);

  lstm_mfma<28><<< 32,256,0,stream>>>(xhat, h1, Wih0,              Whh_all,          bih_all,       bhh_all,       1);
  lstm_mfma<64><<< 64,256,0,stream>>>(h1,   h2, Wih_rest,          Whh_all+  256*64, bih_all+  256, bhh_all+  256, 2);
  lstm_mfma<64><<<128,256,0,stream>>>(h2,   h3, Wih_rest+256*64,   Whh_all+2*256*64, bih_all+2*256, bhh_all+2*256, 4);
  lstm_mfma<64><<<256,256,0,stream>>>(h3,   h4, Wih_rest+2*256*64, Whh_all+3*256*64, bih_all+3*256, bhh_all+3*256, 8);

  adapter_kernel<<<(T_WIN*512)/64,256,0,stream>>>(h4, h2, adW, adb, out_yhat);
}

// Round 3
// 5343.290 us; speedup vs baseline: 2.2235x; 1.1064x over previous
//
#include <hip/hip_runtime.h>
#include <hip/hip_bf16.h>
#include <cstdio>

typedef __hip_bfloat16 bf16;
typedef __attribute__((ext_vector_type(8))) short short8v;
typedef __attribute__((ext_vector_type(4))) float f32x4;

#define T_WIN 1993      // N_WINDOWS
#define NSER 512
#define NTIME 2048

__device__ __forceinline__ float sigmf(float x) { return __fdividef(1.f, 1.f + __expf(-x)); }
__device__ __forceinline__ float tanhf_fast(float x) { return 1.f - __fdividef(2.f, __expf(2.f*x) + 1.f); }
__device__ __forceinline__ ushort f2bfu(float f) {
  __hip_bfloat16 h = __float2bfloat16(f);
  return *reinterpret_cast<ushort*>(&h);
}

// ---------------- ES scan: 1 thread per series ----------------
__global__ void es_kernel(const float* __restrict__ y, const int* __restrict__ idxs,
                          const float* __restrict__ lev_sms, const float* __restrict__ seas_sms,
                          const float* __restrict__ init_seas,
                          float* __restrict__ levels, float* __restrict__ seas) {
  int s = blockIdx.x*blockDim.x + threadIdx.x;
  if (s >= NSER) return;
  int id = idxs[s];
  float ls = sigmf(lev_sms[id]);
  float ss = sigmf(seas_sms[id]);
  float buf[8];
  #pragma unroll
  for (int k=0;k<7;++k) buf[k] = __expf(init_seas[id*7+k]);
  buf[7] = buf[0];
  const float* yr = y + (size_t)s*NTIME;
  float* lr = levels + (size_t)s*NTIME;
  float* sr = seas + (size_t)s*NTIME;
  float lev = __fdividef(yr[0], buf[0]);
  lr[0] = lev;
  #pragma unroll
  for (int t=0;t<8;++t) sr[t] = buf[t];
  #pragma unroll 8
  for (int t=1;t<NTIME;++t) {
    float yt = yr[t];
    float st = buf[1];
    lev = ls*__fdividef(yt,st) + (1.f-ls)*lev;
    float ns = ss*__fdividef(yt,lev) + (1.f-ss)*st;
    #pragma unroll
    for (int k=0;k<7;++k) buf[k] = buf[k+1];
    buf[7] = ns;
    lr[t] = lev;
    if (t+7 < NTIME) sr[t+7] = ns;
  }
}

// ---------------- log(norm), log(levels) ----------------
__global__ void lnorm_kernel(const float* __restrict__ y, const float* __restrict__ seas,
                             const float* __restrict__ levels,
                             float* __restrict__ lnorm, float* __restrict__ llev) {
  int i = blockIdx.x*256 + threadIdx.x;
  lnorm[i] = __logf(__fdividef(y[i], seas[i]));
  llev[i]  = __logf(levels[i]);
}

// ---------------- windows: windows_y (out0) + RNN input xhat ----------------
__global__ void window_kernel(const float* __restrict__ lnorm, const float* __restrict__ llev,
                              const float* __restrict__ noise,
                              float* __restrict__ wy, ushort* __restrict__ xhat) {
  int idx = blockIdx.x*256 + threadIdx.x;   // (w*512 + s)*28 + k
  int k  = idx % 28;
  int rs = idx / 28;
  int s  = rs & 511;
  int w  = rs >> 9;
  float lv = llev[s*NTIME + 28 + w];
  const float* Ln = lnorm + s*NTIME;
  wy[idx]   = Ln[w+28+k] - lv;
  xhat[idx] = f2bfu(Ln[w+k] - lv + 0.001f*noise[idx]);
}

// ---------------- MFMA dilated LSTM scan: 16 sequences per block -----------
// Wave w owns hidden units [16w,16w+16), all 4 gates (permuted weight rows).
// Z = [x_t | h] @ [Wih | Whh]^T via mfma_f32_16x16x32_bf16, M=16 batch.
// x A-fragments loaded global->VGPR directly, prefetched 2 steps ahead.
// h exchanged via double-buffered LDS with a RAW s_barrier (lgkmcnt-only wait)
// so hout stores and x prefetch loads stay in flight across steps.
template<int D>
__global__ __launch_bounds__(256, 1)
void lstm_mfma(const ushort* __restrict__ xin, ushort* __restrict__ hout,
               const float* __restrict__ Wih, const float* __restrict__ Whh,
               const float* __restrict__ bih, const float* __restrict__ bhh,
               const int rate) {
  constexpr int KXS = (D == 28) ? 1 : 2;   // x k-steps
  constexpr int KST = KXS + 2;             // + 2 h k-steps
  constexpr int KX  = KXS * 32;

  __shared__ ushort hbuf[2][16*72];        // stride 72: 2-way (free) banks

  const int i    = threadIdx.x;
  const int lane = i & 63;
  const int wid  = i >> 6;
  const int n15  = lane & 15;              // A row (batch) / B col (unit)
  const int kq   = lane >> 4;              // k-quarter
  const int j    = blockIdx.x >> 5;        // dilation phase
  const int base = (blockIdx.x & 31) * 16; // series group

  // ---- weight B-fragments (permuted rows: gate g, unit 16*wid+n15) ----
  short8v wfrag[4][KST];
  float bias[4];
  #pragma unroll
  for (int g = 0; g < 4; ++g) {
    const int R = g*64 + wid*16 + n15;
    bias[g] = bih[R] + bhh[R];
    #pragma unroll
    for (int kk = 0; kk < KST; ++kk) {
      #pragma unroll
      for (int jj = 0; jj < 8; ++jj) {
        const int k = kk*32 + kq*8 + jj;
        float v;
        if (k < KX) v = (k < D) ? Wih[R*D + k] : 0.f;
        else        v = Whh[R*64 + (k - KX)];
        wfrag[g][kk][jj] = (short)f2bfu(v);
      }
    }
  }

  for (int e = i; e < 1152; e += 256) hbuf[0][e] = 0;
  __syncthreads();

  const int nsteps = (T_WIN - 1 - j)/rate + 1;
  const int u = wid*16 + n15;
  float cc[4] = {0.f, 0.f, 0.f, 0.f};

  // direct global A-fragment load for time t (clamped in-bounds for prefetch)
  auto loadx = [&](int t, short8v* xf) {
    const int tc = (t < T_WIN) ? t : (T_WIN - 1);
    const ushort* p = xin + ((size_t)tc*512 + base + n15)*(size_t)D + kq*8;
    if constexpr (D == 64) {
      xf[0] = *reinterpret_cast<const short8v*>(p);
      xf[1] = *reinterpret_cast<const short8v*>(p + 32);
    } else {
      ushort4 a = *reinterpret_cast<const ushort4*>(p);
      ushort4 b = *reinterpret_cast<const ushort4*>(p + 4);  // cols 28..31 of row (pad)
      if (kq == 3) { b.x = 0; b.y = 0; b.z = 0; b.w = 0; }   // zero the K-pad
      short8v r;
      r[0]=(short)a.x; r[1]=(short)a.y; r[2]=(short)a.z; r[3]=(short)a.w;
      r[4]=(short)b.x; r[5]=(short)b.y; r[6]=(short)b.z; r[7]=(short)b.w;
      xf[0] = r;
    }
  };

  // one recurrence step; xf was loaded >=2 steps ago; reloads xf for step S+2
  auto step = [&](int S, short8v* xf) {
    const int p_ = S & 1;
    const int t_ = j + S*rate;
    short8v hf0 = *reinterpret_cast<const short8v*>(&hbuf[p_][n15*72 + kq*8]);
    short8v hf1 = *reinterpret_cast<const short8v*>(&hbuf[p_][n15*72 + 32 + kq*8]);
    f32x4 acc0 = {bias[0], bias[0], bias[0], bias[0]};
    f32x4 acc1 = {bias[1], bias[1], bias[1], bias[1]};
    f32x4 acc2 = {bias[2], bias[2], bias[2], bias[2]};
    f32x4 acc3 = {bias[3], bias[3], bias[3], bias[3]};
    #pragma unroll
    for (int kk = 0; kk < KXS; ++kk) {
      acc0 = __builtin_amdgcn_mfma_f32_16x16x32_bf16(xf[kk], wfrag[0][kk], acc0, 0, 0, 0);
      acc1 = __builtin_amdgcn_mfma_f32_16x16x32_bf16(xf[kk], wfrag[1][kk], acc1, 0, 0, 0);
      acc2 = __builtin_amdgcn_mfma_f32_16x16x32_bf16(xf[kk], wfrag[2][kk], acc2, 0, 0, 0);
      acc3 = __builtin_amdgcn_mfma_f32_16x16x32_bf16(xf[kk], wfrag[3][kk], acc3, 0, 0, 0);
    }
    acc0 = __builtin_amdgcn_mfma_f32_16x16x32_bf16(hf0, wfrag[0][KXS], acc0, 0, 0, 0);
    acc1 = __builtin_amdgcn_mfma_f32_16x16x32_bf16(hf0, wfrag[1][KXS], acc1, 0, 0, 0);
    acc2 = __builtin_amdgcn_mfma_f32_16x16x32_bf16(hf0, wfrag[2][KXS], acc2, 0, 0, 0);
    acc3 = __builtin_amdgcn_mfma_f32_16x16x32_bf16(hf0, wfrag[3][KXS], acc3, 0, 0, 0);
    acc0 = __builtin_amdgcn_mfma_f32_16x16x32_bf16(hf1, wfrag[0][KXS+1], acc0, 0, 0, 0);
    acc1 = __builtin_amdgcn_mfma_f32_16x16x32_bf16(hf1, wfrag[1][KXS+1], acc1, 0, 0, 0);
    acc2 = __builtin_amdgcn_mfma_f32_16x16x32_bf16(hf1, wfrag[2][KXS+1], acc2, 0, 0, 0);
    acc3 = __builtin_amdgcn_mfma_f32_16x16x32_bf16(hf1, wfrag[3][KXS+1], acc3, 0, 0, 0);
    // prefetch x for step S+2 into the same register set (consumed above)
    loadx(t_ + 2*rate, xf);
    // gates: lane holds z_i,z_f,z_g,z_o for (batch m=kq*4+r, unit u) in reg r
    #pragma unroll
    for (int r = 0; r < 4; ++r) {
      const float zi = acc0[r], zf = acc1[r], zg = acc2[r], zo = acc3[r];
      cc[r] = sigmf(zf)*cc[r] + sigmf(zi)*tanhf_fast(zg);
      const float h_ = sigmf(zo)*tanhf_fast(cc[r]);
      const ushort hu = f2bfu(h_);
      const int m_ = kq*4 + r;
      hbuf[p_^1][m_*72 + u] = hu;
      hout[((size_t)t_*512 + base + m_)*64 + u] = hu;   // fire-and-forget
    }
    // order LDS h-writes across waves WITHOUT draining vmcnt (stores/prefetch
    // stay in flight) — this was the 4x per-step stall with __syncthreads()
    asm volatile("s_waitcnt lgkmcnt(0)\n\ts_barrier" ::: "memory");
  };

  short8v xf0[KXS], xf1[KXS];
  loadx(j, xf0);
  loadx(j + rate, xf1);
  int s = 0;
  for (; s + 1 < nsteps; s += 2) {
    step(s,   xf0);
    step(s+1, xf1);
  }
  if (s < nsteps) step(s, xf0);
}

// ---------------- adapter: out1 = (h4+h2) @ adW.T + adb ----------------
__global__ __launch_bounds__(256) void adapter_kernel(const ushort* __restrict__ h4, const ushort* __restrict__ h2,
      const float* __restrict__ adW, const float* __restrict__ adb, float* __restrict__ out) {
  __shared__ __align__(16) float xrow[64*64];
  const int i = threadIdx.x;
  const int total = T_WIN*512;
  const int base = blockIdx.x * 64;
  for (int e = i; e < 64*64; e += 256) {
    int r = e >> 6;
    size_t gi = (size_t)(base + r)*64 + (e & 63);
    float v = 0.f;
    if (base + r < total) {
      __hip_bfloat16 a = *reinterpret_cast<const __hip_bfloat16*>(h4 + gi);
      __hip_bfloat16 b = *reinterpret_cast<const __hip_bfloat16*>(h2 + gi);
      v = __bfloat162float(a) + __bfloat162float(b);
    }
    xrow[e] = v;
  }
  const int o  = i & 31;
  const int rg = i >> 5;
  float w[64]; float bo = 0.f;
  if (o < 28) {
    #pragma unroll
    for (int uu=0;uu<64;++uu) w[uu] = adW[o*64+uu];
    bo = adb[o];
  }
  __syncthreads();
  if (o < 28) {
    #pragma unroll
    for (int rr=0; rr<8; ++rr) {
      int r = rg*8 + rr;
      if (base + r >= total) break;
      const float4* xp = (const float4*)(&xrow[r*64]);
      float a0 = bo, a1 = 0.f, a2 = 0.f, a3 = 0.f;
      #pragma unroll
      for (int q=0;q<16;++q) {
        float4 xv = xp[q];
        a0 += w[4*q+0]*xv.x; a1 += w[4*q+1]*xv.y;
        a2 += w[4*q+2]*xv.z; a3 += w[4*q+3]*xv.w;
      }
      out[(size_t)(base+r)*28 + o] = (a0+a1)+(a2+a3);
    }
  }
}

extern "C" void kernel_launch(void* const* d_in, const int* in_sizes, int n_in,
                              void* d_out, int out_size, void* d_ws, size_t ws_size,
                              hipStream_t stream) {
  const float* y         = (const float*)d_in[0];
  const int*   idxs      = (const int*)d_in[1];
  const float* noise     = (const float*)d_in[2];
  const float* lev_sms   = (const float*)d_in[3];
  const float* seas_sms  = (const float*)d_in[4];
  const float* init_seas = (const float*)d_in[5];
  const float* Wih0      = (const float*)d_in[6];
  const float* Wih_rest  = (const float*)d_in[7];
  const float* Whh_all   = (const float*)d_in[8];
  const float* bih_all   = (const float*)d_in[9];
  const float* bhh_all   = (const float*)d_in[10];
  const float* adW       = (const float*)d_in[11];
  const float* adb       = (const float*)d_in[12];

  const size_t NWIN28 = (size_t)T_WIN*512*28;
  const size_t NWIN64 = (size_t)T_WIN*512*64;
  float* out_wy   = (float*)d_out;
  float* out_yhat = out_wy + NWIN28;
  float* out_lev  = out_yhat + NWIN28;

  float* seas  = (float*)d_ws;
  float* lnorm = seas  + (size_t)NSER*NTIME;
  float* llev  = lnorm + (size_t)NSER*NTIME;
  ushort* xhat = (ushort*)(llev + (size_t)NSER*NTIME);
  ushort* h1   = (ushort*)((char*)xhat + NWIN28*2);
  ushort* h2   = (ushort*)((char*)h1 + NWIN64*2);
  ushort* h4   = (ushort*)((char*)h2 + NWIN64*2);
  ushort* h3   = h1;  // reuse: h1 dead once layer 3 starts

  size_t need = (size_t)3*NSER*NTIME*4 + NWIN28*2 + 3*NWIN64*2;
  if (ws_size < need) {
    fprintf(stderr, "kernel_launch: ws_size %zu < needed %zu\n", ws_size, need);
    return;
  }

  es_kernel<<<2,256,0,stream>>>(y, idxs, lev_sms, seas_sms, init_seas, out_lev, seas);
  lnorm_kernel<<<(NSER*NTIME)/256,256,0,stream>>>(y, seas, out_lev, lnorm, llev);
  window_kernel<<<NWIN28/256,256,0,stream>>>(lnorm, llev, noise, out_wy, xhat);

  lstm_mfma<28><<< 32,256,0,stream>>>(xhat, h1, Wih0,              Whh_all,          bih_all,       bhh_all,       1);
  lstm_mfma<64><<< 64,256,0,stream>>>(h1,   h2, Wih_rest,          Whh_all+  256*64, bih_all+  256, bhh_all+  256, 2);
  lstm_mfma<64><<<128,256,0,stream>>>(h2,   h3, Wih_rest+256*64,   Whh_all+2*256*64, bih_all+2*256, bhh_all+2*256, 4);
  lstm_mfma<64><<<256,256,0,stream>>>(h3,   h4, Wih_rest+2*256*64, Whh_all+3*256*64, bih_all+3*256, bhh_all+3*256, 8);

  adapter_kernel<<<(T_WIN*512)/64,256,0,stream>>>(h4, h2, adW, adb, out_yhat);
}

// Round 4
// 5237.765 us; speedup vs baseline: 2.2683x; 1.0201x over previous
//
#include <hip/hip_runtime.h>
#include <hip/hip_bf16.h>
#include <cstdio>

typedef __hip_bfloat16 bf16;
typedef __attribute__((ext_vector_type(8))) short short8v;
typedef __attribute__((ext_vector_type(4))) float f32x4;

#define T_WIN 1993      // N_WINDOWS
#define NSER 512
#define NTIME 2048

__device__ __forceinline__ float sigmf(float x) { return __fdividef(1.f, 1.f + __expf(-x)); }
__device__ __forceinline__ float tanhf_fast(float x) { return 1.f - __fdividef(2.f, __expf(2.f*x) + 1.f); }
__device__ __forceinline__ ushort f2bfu(float f) {
  __hip_bfloat16 h = __float2bfloat16(f);
  return *reinterpret_cast<ushort*>(&h);
}

// ---------------- ES scan: 1 thread per series ----------------
__global__ void es_kernel(const float* __restrict__ y, const int* __restrict__ idxs,
                          const float* __restrict__ lev_sms, const float* __restrict__ seas_sms,
                          const float* __restrict__ init_seas,
                          float* __restrict__ levels, float* __restrict__ seas) {
  int s = blockIdx.x*blockDim.x + threadIdx.x;
  if (s >= NSER) return;
  int id = idxs[s];
  float ls = sigmf(lev_sms[id]);
  float ss = sigmf(seas_sms[id]);
  float buf[8];
  #pragma unroll
  for (int k=0;k<7;++k) buf[k] = __expf(init_seas[id*7+k]);
  buf[7] = buf[0];
  const float* yr = y + (size_t)s*NTIME;
  float* lr = levels + (size_t)s*NTIME;
  float* sr = seas + (size_t)s*NTIME;
  float lev = __fdividef(yr[0], buf[0]);
  lr[0] = lev;
  #pragma unroll
  for (int t=0;t<8;++t) sr[t] = buf[t];
  #pragma unroll 8
  for (int t=1;t<NTIME;++t) {
    float yt = yr[t];
    float st = buf[1];
    lev = ls*__fdividef(yt,st) + (1.f-ls)*lev;
    float ns = ss*__fdividef(yt,lev) + (1.f-ss)*st;
    #pragma unroll
    for (int k=0;k<7;++k) buf[k] = buf[k+1];
    buf[7] = ns;
    lr[t] = lev;
    if (t+7 < NTIME) sr[t+7] = ns;
  }
}

// ---------------- log(norm), log(levels) ----------------
__global__ void lnorm_kernel(const float* __restrict__ y, const float* __restrict__ seas,
                             const float* __restrict__ levels,
                             float* __restrict__ lnorm, float* __restrict__ llev) {
  int i = blockIdx.x*256 + threadIdx.x;
  lnorm[i] = __logf(__fdividef(y[i], seas[i]));
  llev[i]  = __logf(levels[i]);
}

// ---------------- windows: windows_y (out0) + RNN input xhat ----------------
__global__ void window_kernel(const float* __restrict__ lnorm, const float* __restrict__ llev,
                              const float* __restrict__ noise,
                              float* __restrict__ wy, ushort* __restrict__ xhat) {
  int idx = blockIdx.x*256 + threadIdx.x;   // (w*512 + s)*28 + k
  int k  = idx % 28;
  int rs = idx / 28;
  int s  = rs & 511;
  int w  = rs >> 9;
  float lv = llev[s*NTIME + 28 + w];
  const float* Ln = lnorm + s*NTIME;
  wy[idx]   = Ln[w+28+k] - lv;
  xhat[idx] = f2bfu(Ln[w+k] - lv + 0.001f*noise[idx]);
}

// ---------------- MFMA dilated LSTM scan: 16 sequences per block -----------
// Wave w owns hidden units [16w,16w+16), all 4 gates (permuted weight rows).
// Z = [x_t | h] @ [Wih | Whh]^T via mfma_f32_16x16x32_bf16, M=16 batch.
// x A-fragments: direct global->VGPR, prefetched 2 steps ahead.
// h exchange: double-buffered LDS; per-step sync is sched_barrier(0) +
// "s_waitcnt lgkmcnt(0)" (NO memory clobber -> no forced vmcnt drain) +
// __builtin_amdgcn_s_barrier(). hout written as a LAGGED COALESCED store
// from LDS (one dwordx2 per thread) instead of 4 scattered 2B stores.
template<int D>
__global__ __launch_bounds__(256, 1)
void lstm_mfma(const ushort* __restrict__ xin, ushort* __restrict__ hout,
               const float* __restrict__ Wih, const float* __restrict__ Whh,
               const float* __restrict__ bih, const float* __restrict__ bhh,
               const int rate) {
  constexpr int KXS = (D == 28) ? 1 : 2;   // x k-steps
  constexpr int KST = KXS + 2;             // + 2 h k-steps
  constexpr int KX  = KXS * 32;

  __shared__ __align__(16) ushort hbuf[2][16*72];  // stride 72 units (144B)

  const int i    = threadIdx.x;
  const int lane = i & 63;
  const int wid  = i >> 6;
  const int n15  = lane & 15;              // A row (batch) / B col (unit)
  const int kq   = lane >> 4;              // k-quarter
  const int j    = blockIdx.x >> 5;        // dilation phase
  const int base = (blockIdx.x & 31) * 16; // series group
  const int wm   = i >> 4;                 // writeback row 0..15
  const int wu   = (i & 15) * 4;           // writeback unit group

  // ---- weight B-fragments (permuted rows: gate g, unit 16*wid+n15) ----
  short8v wfrag[4][KST];
  float bias[4];
  #pragma unroll
  for (int g = 0; g < 4; ++g) {
    const int R = g*64 + wid*16 + n15;
    bias[g] = bih[R] + bhh[R];
    #pragma unroll
    for (int kk = 0; kk < KST; ++kk) {
      #pragma unroll
      for (int jj = 0; jj < 8; ++jj) {
        const int k = kk*32 + kq*8 + jj;
        float v;
        if (k < KX) v = (k < D) ? Wih[R*D + k] : 0.f;
        else        v = Whh[R*64 + (k - KX)];
        wfrag[g][kk][jj] = (short)f2bfu(v);
      }
    }
  }

  for (int e = i; e < 1152; e += 256) hbuf[0][e] = 0;
  __syncthreads();

  const int nsteps = (T_WIN - 1 - j)/rate + 1;
  const int u = wid*16 + n15;
  float cc[4] = {0.f, 0.f, 0.f, 0.f};

  // direct global A-fragment load for time t (clamped in-bounds for prefetch)
  auto loadx = [&](int t, short8v* xf) {
    const int tc = (t < T_WIN) ? t : (T_WIN - 1);
    const ushort* p = xin + ((size_t)tc*512 + base + n15)*(size_t)D + kq*8;
    if constexpr (D == 64) {
      xf[0] = *reinterpret_cast<const short8v*>(p);
      xf[1] = *reinterpret_cast<const short8v*>(p + 32);
    } else {
      ushort4 a = *reinterpret_cast<const ushort4*>(p);
      ushort4 b = *reinterpret_cast<const ushort4*>(p + 4);  // cols 28..31 (pad)
      if (kq == 3) { b.x = 0; b.y = 0; b.z = 0; b.w = 0; }   // zero K-pad
      short8v r;
      r[0]=(short)a.x; r[1]=(short)a.y; r[2]=(short)a.z; r[3]=(short)a.w;
      r[4]=(short)b.x; r[5]=(short)b.y; r[6]=(short)b.z; r[7]=(short)b.w;
      xf[0] = r;
    }
  };

  // one recurrence step; xf was loaded >=2 steps ago; reloads xf for step S+2
  auto step = [&](int S, short8v* xf) {
    const int p_ = S & 1;
    const int t_ = j + S*rate;
    __builtin_amdgcn_sched_barrier(0);
    // h A-fragments for this step (h_{S-1}, written pre-barrier last step)
    short8v hf0 = *reinterpret_cast<const short8v*>(&hbuf[p_][n15*72 + kq*8]);
    short8v hf1 = *reinterpret_cast<const short8v*>(&hbuf[p_][n15*72 + 32 + kq*8]);
    // lagged coalesced writeback of h_{S-1} (fills the hf-read latency shadow)
    if (S > 0) {
      uint2 hv = *reinterpret_cast<const uint2*>(&hbuf[p_][wm*72 + wu]);
      *reinterpret_cast<uint2*>(&hout[((size_t)(t_ - rate)*512 + base + wm)*64 + wu]) = hv;
    }
    f32x4 acc0 = {bias[0], bias[0], bias[0], bias[0]};
    f32x4 acc1 = {bias[1], bias[1], bias[1], bias[1]};
    f32x4 acc2 = {bias[2], bias[2], bias[2], bias[2]};
    f32x4 acc3 = {bias[3], bias[3], bias[3], bias[3]};
    #pragma unroll
    for (int kk = 0; kk < KXS; ++kk) {
      acc0 = __builtin_amdgcn_mfma_f32_16x16x32_bf16(xf[kk], wfrag[0][kk], acc0, 0, 0, 0);
      acc1 = __builtin_amdgcn_mfma_f32_16x16x32_bf16(xf[kk], wfrag[1][kk], acc1, 0, 0, 0);
      acc2 = __builtin_amdgcn_mfma_f32_16x16x32_bf16(xf[kk], wfrag[2][kk], acc2, 0, 0, 0);
      acc3 = __builtin_amdgcn_mfma_f32_16x16x32_bf16(xf[kk], wfrag[3][kk], acc3, 0, 0, 0);
    }
    acc0 = __builtin_amdgcn_mfma_f32_16x16x32_bf16(hf0, wfrag[0][KXS], acc0, 0, 0, 0);
    acc1 = __builtin_amdgcn_mfma_f32_16x16x32_bf16(hf0, wfrag[1][KXS], acc1, 0, 0, 0);
    acc2 = __builtin_amdgcn_mfma_f32_16x16x32_bf16(hf0, wfrag[2][KXS], acc2, 0, 0, 0);
    acc3 = __builtin_amdgcn_mfma_f32_16x16x32_bf16(hf0, wfrag[3][KXS], acc3, 0, 0, 0);
    acc0 = __builtin_amdgcn_mfma_f32_16x16x32_bf16(hf1, wfrag[0][KXS+1], acc0, 0, 0, 0);
    acc1 = __builtin_amdgcn_mfma_f32_16x16x32_bf16(hf1, wfrag[1][KXS+1], acc1, 0, 0, 0);
    acc2 = __builtin_amdgcn_mfma_f32_16x16x32_bf16(hf1, wfrag[2][KXS+1], acc2, 0, 0, 0);
    acc3 = __builtin_amdgcn_mfma_f32_16x16x32_bf16(hf1, wfrag[3][KXS+1], acc3, 0, 0, 0);
    // prefetch x for step S+2 into the just-consumed register set
    loadx(t_ + 2*rate, xf);
    // gates: lane holds z_i,z_f,z_g,z_o for (batch m=kq*4+r, unit u) in reg r
    #pragma unroll
    for (int r = 0; r < 4; ++r) {
      const float zi = acc0[r], zf = acc1[r], zg = acc2[r], zo = acc3[r];
      cc[r] = sigmf(zf)*cc[r] + sigmf(zi)*tanhf_fast(zg);
      const float h_ = sigmf(zo)*tanhf_fast(cc[r]);
      hbuf[p_^1][(kq*4 + r)*72 + u] = f2bfu(h_);
    }
    // order own LDS writes, then barrier — NO memory clobber, so no vmcnt
    // drain: hout stores + x prefetch stay in flight across the barrier.
    __builtin_amdgcn_sched_barrier(0);
    asm volatile("s_waitcnt lgkmcnt(0)");
    __builtin_amdgcn_sched_barrier(0);
    __builtin_amdgcn_s_barrier();
  };

  short8v xf0[KXS], xf1[KXS];
  loadx(j, xf0);
  loadx(j + rate, xf1);
  int s = 0;
  for (; s + 1 < nsteps; s += 2) {
    step(s,   xf0);
    step(s+1, xf1);
  }
  if (s < nsteps) step(s, xf0);

  // final h writeback (h_{nsteps-1} lives in hbuf[nsteps&1])
  {
    const int pF = nsteps & 1;
    const int tF = j + (nsteps - 1)*rate;
    uint2 hv = *reinterpret_cast<const uint2*>(&hbuf[pF][wm*72 + wu]);
    *reinterpret_cast<uint2*>(&hout[((size_t)tF*512 + base + wm)*64 + wu]) = hv;
  }
}

// ---------------- adapter: out1 = (h4+h2) @ adW.T + adb ----------------
__global__ __launch_bounds__(256) void adapter_kernel(const ushort* __restrict__ h4, const ushort* __restrict__ h2,
      const float* __restrict__ adW, const float* __restrict__ adb, float* __restrict__ out) {
  __shared__ __align__(16) float xrow[64*64];
  const int i = threadIdx.x;
  const int total = T_WIN*512;
  const int base = blockIdx.x * 64;
  for (int e = i; e < 64*64; e += 256) {
    int r = e >> 6;
    size_t gi = (size_t)(base + r)*64 + (e & 63);
    float v = 0.f;
    if (base + r < total) {
      __hip_bfloat16 a = *reinterpret_cast<const __hip_bfloat16*>(h4 + gi);
      __hip_bfloat16 b = *reinterpret_cast<const __hip_bfloat16*>(h2 + gi);
      v = __bfloat162float(a) + __bfloat162float(b);
    }
    xrow[e] = v;
  }
  const int o  = i & 31;
  const int rg = i >> 5;
  float w[64]; float bo = 0.f;
  if (o < 28) {
    #pragma unroll
    for (int uu=0;uu<64;++uu) w[uu] = adW[o*64+uu];
    bo = adb[o];
  }
  __syncthreads();
  if (o < 28) {
    #pragma unroll
    for (int rr=0; rr<8; ++rr) {
      int r = rg*8 + rr;
      if (base + r >= total) break;
      const float4* xp = (const float4*)(&xrow[r*64]);
      float a0 = bo, a1 = 0.f, a2 = 0.f, a3 = 0.f;
      #pragma unroll
      for (int q=0;q<16;++q) {
        float4 xv = xp[q];
        a0 += w[4*q+0]*xv.x; a1 += w[4*q+1]*xv.y;
        a2 += w[4*q+2]*xv.z; a3 += w[4*q+3]*xv.w;
      }
      out[(size_t)(base+r)*28 + o] = (a0+a1)+(a2+a3);
    }
  }
}

extern "C" void kernel_launch(void* const* d_in, const int* in_sizes, int n_in,
                              void* d_out, int out_size, void* d_ws, size_t ws_size,
                              hipStream_t stream) {
  const float* y         = (const float*)d_in[0];
  const int*   idxs      = (const int*)d_in[1];
  const float* noise     = (const float*)d_in[2];
  const float* lev_sms   = (const float*)d_in[3];
  const float* seas_sms  = (const float*)d_in[4];
  const float* init_seas = (const float*)d_in[5];
  const float* Wih0      = (const float*)d_in[6];
  const float* Wih_rest  = (const float*)d_in[7];
  const float* Whh_all   = (const float*)d_in[8];
  const float* bih_all   = (const float*)d_in[9];
  const float* bhh_all   = (const float*)d_in[10];
  const float* adW       = (const float*)d_in[11];
  const float* adb       = (const float*)d_in[12];

  const size_t NWIN28 = (size_t)T_WIN*512*28;
  const size_t NWIN64 = (size_t)T_WIN*512*64;
  float* out_wy   = (float*)d_out;
  float* out_yhat = out_wy + NWIN28;
  float* out_lev  = out_yhat + NWIN28;

  float* seas  = (float*)d_ws;
  float* lnorm = seas  + (size_t)NSER*NTIME;
  float* llev  = lnorm + (size_t)NSER*NTIME;
  ushort* xhat = (ushort*)(llev + (size_t)NSER*NTIME);
  ushort* h1   = (ushort*)((char*)xhat + NWIN28*2);
  ushort* h2   = (ushort*)((char*)h1 + NWIN64*2);
  ushort* h4   = (ushort*)((char*)h2 + NWIN64*2);
  ushort* h3   = h1;  // reuse: h1 dead once layer 3 starts

  size_t need = (size_t)3*NSER*NTIME*4 + NWIN28*2 + 3*NWIN64*2;
  if (ws_size < need) {
    fprintf(stderr, "kernel_launch: ws_size %zu < needed %zu\n", ws_size, need);
    return;
  }

  es_kernel<<<2,256,0,stream>>>(y, idxs, lev_sms, seas_sms, init_seas, out_lev, seas);
  lnorm_kernel<<<(NSER*NTIME)/256,256,0,stream>>>(y, seas, out_lev, lnorm, llev);
  window_kernel<<<NWIN28/256,256,0,stream>>>(lnorm, llev, noise, out_wy, xhat);

  lstm_mfma<28><<< 32,256,0,stream>>>(xhat, h1, Wih0,              Whh_all,          bih_all,       bhh_all,       1);
  lstm_mfma<64><<< 64,256,0,stream>>>(h1,   h2, Wih_rest,          Whh_all+  256*64, bih_all+  256, bhh_all+  256, 2);
  lstm_mfma<64><<<128,256,0,stream>>>(h2,   h3, Wih_rest+256*64,   Whh_all+2*256*64, bih_all+2*256, bhh_all+2*256, 4);
  lstm_mfma<64><<<256,256,0,stream>>>(h3,   h4, Wih_rest+2*256*64, Whh_all+3*256*64, bih_all+3*256, bhh_all+3*256, 8);

  adapter_kernel<<<(T_WIN*512)/64,256,0,stream>>>(h4, h2, adW, adb, out_yhat);
}

// Round 5
// 3965.182 us; speedup vs baseline: 2.9962x; 1.3209x over previous
//
#include <hip/hip_runtime.h>
#include <hip/hip_bf16.h>
#include <cstdio>

typedef __hip_bfloat16 bf16;
typedef __attribute__((ext_vector_type(8))) short short8v;
typedef __attribute__((ext_vector_type(4))) float f32x4;

#define T_WIN 1993      // N_WINDOWS
#define NSER 512
#define NTIME 2048
#define NGRP 32
#define FLAGS_INTS (3*8*NGRP)   // [producer layer 0..2][phase 0..7][group]

__device__ __forceinline__ float sigmf(float x) { return __fdividef(1.f, 1.f + __expf(-x)); }
__device__ __forceinline__ float tanhf_fast(float x) { return 1.f - __fdividef(2.f, __expf(2.f*x) + 1.f); }
__device__ __forceinline__ ushort f2bfu(float f) {
  __hip_bfloat16 h = __float2bfloat16(f);
  return *reinterpret_cast<ushort*>(&h);
}

// ---------------- ES scan: 1 thread per series ----------------
__global__ void es_kernel(const float* __restrict__ y, const int* __restrict__ idxs,
                          const float* __restrict__ lev_sms, const float* __restrict__ seas_sms,
                          const float* __restrict__ init_seas,
                          float* __restrict__ levels, float* __restrict__ seas) {
  int s = blockIdx.x*blockDim.x + threadIdx.x;
  if (s >= NSER) return;
  int id = idxs[s];
  float ls = sigmf(lev_sms[id]);
  float ss = sigmf(seas_sms[id]);
  float buf[8];
  #pragma unroll
  for (int k=0;k<7;++k) buf[k] = __expf(init_seas[id*7+k]);
  buf[7] = buf[0];
  const float* yr = y + (size_t)s*NTIME;
  float* lr = levels + (size_t)s*NTIME;
  float* sr = seas + (size_t)s*NTIME;
  float lev = __fdividef(yr[0], buf[0]);
  lr[0] = lev;
  #pragma unroll
  for (int t=0;t<8;++t) sr[t] = buf[t];
  #pragma unroll 8
  for (int t=1;t<NTIME;++t) {
    float yt = yr[t];
    float st = buf[1];
    lev = ls*__fdividef(yt,st) + (1.f-ls)*lev;
    float ns = ss*__fdividef(yt,lev) + (1.f-ss)*st;
    #pragma unroll
    for (int k=0;k<7;++k) buf[k] = buf[k+1];
    buf[7] = ns;
    lr[t] = lev;
    if (t+7 < NTIME) sr[t+7] = ns;
  }
}

// ---------------- log(norm), log(levels) ----------------
__global__ void lnorm_kernel(const float* __restrict__ y, const float* __restrict__ seas,
                             const float* __restrict__ levels,
                             float* __restrict__ lnorm, float* __restrict__ llev) {
  int i = blockIdx.x*256 + threadIdx.x;
  lnorm[i] = __logf(__fdividef(y[i], seas[i]));
  llev[i]  = __logf(levels[i]);
}

// ---------------- windows: windows_y (out0) + RNN input xhat ----------------
__global__ void window_kernel(const float* __restrict__ lnorm, const float* __restrict__ llev,
                              const float* __restrict__ noise,
                              float* __restrict__ wy, ushort* __restrict__ xhat) {
  int idx = blockIdx.x*256 + threadIdx.x;   // (w*512 + s)*28 + k
  int k  = idx % 28;
  int rs = idx / 28;
  int s  = rs & 511;
  int w  = rs >> 9;
  float lv = llev[s*NTIME + 28 + w];
  const float* Ln = lnorm + s*NTIME;
  wy[idx]   = Ln[w+28+k] - lv;
  xhat[idx] = f2bfu(Ln[w+k] - lv + 0.001f*noise[idx]);
}

// ---------------- fused 4-layer pipelined LSTM scan ----------------
// Per block: 16 series, one (layer, phase). Wave w owns units [16w,16w+16),
// all 4 gates. Cross-layer handoff via per-(layer,phase,group) progress
// flags: flag F (agent-scope release) means "h stored for steps < F".
template<int KXS>
__device__ __forceinline__ void lstm_scan(
    const ushort* __restrict__ xin, ushort* __restrict__ hout,
    const float* __restrict__ Wih, const float* __restrict__ Whh,
    const float* __restrict__ bih, const float* __restrict__ bhh,
    const int rate, const int j, const int g, const int layer,
    int* __restrict__ flags)
{
  constexpr int KST = KXS + 2;
  constexpr int D   = (KXS == 1) ? 28 : 64;
  constexpr int KX  = KXS * 32;

  __shared__ __align__(16) ushort hbuf[2][16*72];

  const int i    = threadIdx.x;
  const int lane = i & 63;
  const int wid  = i >> 6;
  const int n15  = lane & 15;
  const int kq   = lane >> 4;
  const int base = g * 16;
  const int wm   = i >> 4;
  const int wu   = (i & 15) * 4;

  // ---- weight B-fragments (permuted rows: gate gg, unit 16*wid+n15) ----
  short8v wfrag[4][KST];
  float bias[4];
  #pragma unroll
  for (int gg = 0; gg < 4; ++gg) {
    const int R = gg*64 + wid*16 + n15;
    bias[gg] = bih[R] + bhh[R];
    #pragma unroll
    for (int kk = 0; kk < KST; ++kk) {
      #pragma unroll
      for (int jj = 0; jj < 8; ++jj) {
        const int k = kk*32 + kq*8 + jj;
        float v;
        if (k < KX) v = (k < D) ? Wih[R*D + k] : 0.f;
        else        v = Whh[R*64 + (k - KX)];
        wfrag[gg][kk][jj] = (short)f2bfu(v);
      }
    }
  }

  for (int e = i; e < 1152; e += 256) hbuf[0][e] = 0;
  __syncthreads();

  const int nsteps = (T_WIN - 1 - j)/rate + 1;
  const int u = wid*16 + n15;
  float cc[4] = {0.f, 0.f, 0.f, 0.f};

  // ---- flag plumbing ----
  int* myflag = &flags[(layer*8 + j)*NGRP + g];
  const int srcrate = rate >> 1;           // producer's rate (layer>=1)
  int* srcbase = (layer > 0) ? &flags[((layer-1)*8)*NGRP + g] : nullptr;
  const int pp0 = (layer > 0) ? (j % srcrate) : 0;
  int seen0 = 0;

  auto wait_for = [&](int t) {
    if (layer == 0) return;
    const int tc = (t < T_WIN) ? t : (T_WIN - 1);
    const int pp = tc % srcrate;
    const int need = tc / srcrate + 1;
    if (pp == pp0 && seen0 >= need) return;
    int* fp = srcbase + pp*NGRP;
    if (__hip_atomic_load(fp, __ATOMIC_RELAXED, __HIP_MEMORY_SCOPE_AGENT) < need) {
      while (__hip_atomic_load(fp, __ATOMIC_RELAXED, __HIP_MEMORY_SCOPE_AGENT) < need)
        __builtin_amdgcn_s_sleep(8);
    }
    int v = __hip_atomic_load(fp, __ATOMIC_ACQUIRE, __HIP_MEMORY_SCOPE_AGENT);
    if (pp == pp0) seen0 = v;
  };

  auto loadx = [&](int t, short8v* xf) {
    const int tc = (t < T_WIN) ? t : (T_WIN - 1);
    const ushort* p = xin + ((size_t)tc*512 + base + n15)*(size_t)D + kq*8;
    if constexpr (D == 64) {
      xf[0] = *reinterpret_cast<const short8v*>(p);
      xf[1] = *reinterpret_cast<const short8v*>(p + 32);
    } else {
      ushort4 a = *reinterpret_cast<const ushort4*>(p);
      ushort4 b = *reinterpret_cast<const ushort4*>(p + 4);
      if (kq == 3) { b.x = 0; b.y = 0; b.z = 0; b.w = 0; }
      short8v r;
      r[0]=(short)a.x; r[1]=(short)a.y; r[2]=(short)a.z; r[3]=(short)a.w;
      r[4]=(short)b.x; r[5]=(short)b.y; r[6]=(short)b.z; r[7]=(short)b.w;
      xf[0] = r;
    }
  };

  auto step = [&](int S, short8v* xf) {
    const int p_ = S & 1;
    const int t_ = j + S*rate;
    __builtin_amdgcn_sched_barrier(0);
    short8v hf0 = *reinterpret_cast<const short8v*>(&hbuf[p_][n15*72 + kq*8]);
    short8v hf1 = *reinterpret_cast<const short8v*>(&hbuf[p_][n15*72 + 32 + kq*8]);
    // lagged coalesced writeback of h_{S-1}
    if (S > 0) {
      uint2 hv = *reinterpret_cast<const uint2*>(&hbuf[p_][wm*72 + wu]);
      *reinterpret_cast<uint2*>(&hout[((size_t)(t_ - rate)*512 + base + wm)*64 + wu]) = hv;
    }
    f32x4 acc0 = {bias[0], bias[0], bias[0], bias[0]};
    f32x4 acc1 = {bias[1], bias[1], bias[1], bias[1]};
    f32x4 acc2 = {bias[2], bias[2], bias[2], bias[2]};
    f32x4 acc3 = {bias[3], bias[3], bias[3], bias[3]};
    #pragma unroll
    for (int kk = 0; kk < KXS; ++kk) {
      acc0 = __builtin_amdgcn_mfma_f32_16x16x32_bf16(xf[kk], wfrag[0][kk], acc0, 0, 0, 0);
      acc1 = __builtin_amdgcn_mfma_f32_16x16x32_bf16(xf[kk], wfrag[1][kk], acc1, 0, 0, 0);
      acc2 = __builtin_amdgcn_mfma_f32_16x16x32_bf16(xf[kk], wfrag[2][kk], acc2, 0, 0, 0);
      acc3 = __builtin_amdgcn_mfma_f32_16x16x32_bf16(xf[kk], wfrag[3][kk], acc3, 0, 0, 0);
    }
    acc0 = __builtin_amdgcn_mfma_f32_16x16x32_bf16(hf0, wfrag[0][KXS], acc0, 0, 0, 0);
    acc1 = __builtin_amdgcn_mfma_f32_16x16x32_bf16(hf0, wfrag[1][KXS], acc1, 0, 0, 0);
    acc2 = __builtin_amdgcn_mfma_f32_16x16x32_bf16(hf0, wfrag[2][KXS], acc2, 0, 0, 0);
    acc3 = __builtin_amdgcn_mfma_f32_16x16x32_bf16(hf0, wfrag[3][KXS], acc3, 0, 0, 0);
    acc0 = __builtin_amdgcn_mfma_f32_16x16x32_bf16(hf1, wfrag[0][KXS+1], acc0, 0, 0, 0);
    acc1 = __builtin_amdgcn_mfma_f32_16x16x32_bf16(hf1, wfrag[1][KXS+1], acc1, 0, 0, 0);
    acc2 = __builtin_amdgcn_mfma_f32_16x16x32_bf16(hf1, wfrag[2][KXS+1], acc2, 0, 0, 0);
    acc3 = __builtin_amdgcn_mfma_f32_16x16x32_bf16(hf1, wfrag[3][KXS+1], acc3, 0, 0, 0);
    // prefetch x for step S+2 (wait for producer coverage first; usually cached)
    wait_for(t_ + 2*rate);
    loadx(t_ + 2*rate, xf);
    #pragma unroll
    for (int r = 0; r < 4; ++r) {
      const float zi = acc0[r], zf = acc1[r], zg = acc2[r], zo = acc3[r];
      cc[r] = sigmf(zf)*cc[r] + sigmf(zi)*tanhf_fast(zg);
      const float h_ = sigmf(zo)*tanhf_fast(cc[r]);
      hbuf[p_^1][(kq*4 + r)*72 + u] = f2bfu(h_);
    }
    __builtin_amdgcn_sched_barrier(0);
    asm volatile("s_waitcnt lgkmcnt(0)");
    __builtin_amdgcn_sched_barrier(0);
    __builtin_amdgcn_s_barrier();
    // publish progress every 8 steps: h stored for steps < S
    if (layer < 3 && (S & 7) == 7) {
      asm volatile("s_waitcnt vmcnt(0)");
      __builtin_amdgcn_s_barrier();
      if (i == 0)
        __hip_atomic_store(myflag, S, __ATOMIC_RELEASE, __HIP_MEMORY_SCOPE_AGENT);
    }
  };

  short8v xf0[KXS], xf1[KXS];
  wait_for(j);          loadx(j, xf0);
  wait_for(j + rate);   loadx(j + rate, xf1);
  int s = 0;
  for (; s + 1 < nsteps; s += 2) {
    step(s,   xf0);
    step(s+1, xf1);
  }
  if (s < nsteps) step(s, xf0);

  // final h writeback + terminal publish
  {
    const int pF = nsteps & 1;
    const int tF = j + (nsteps - 1)*rate;
    uint2 hv = *reinterpret_cast<const uint2*>(&hbuf[pF][wm*72 + wu]);
    *reinterpret_cast<uint2*>(&hout[((size_t)tF*512 + base + wm)*64 + wu]) = hv;
  }
  if (layer < 3) {
    asm volatile("s_waitcnt vmcnt(0)");
    __builtin_amdgcn_s_barrier();
    if (i == 0)
      __hip_atomic_store(myflag, nsteps, __ATOMIC_RELEASE, __HIP_MEMORY_SCOPE_AGENT);
  }
}

__global__ __launch_bounds__(256, 2)
void lstm_fused(const ushort* __restrict__ xhat,
                ushort* __restrict__ h1, ushort* __restrict__ h2, ushort* __restrict__ h4,
                const float* __restrict__ Wih0, const float* __restrict__ Wih_rest,
                const float* __restrict__ Whh_all,
                const float* __restrict__ bih_all, const float* __restrict__ bhh_all,
                int* __restrict__ flags)
{
  const int bid = blockIdx.x;
  int layer, rate, j, g;
  if (bid < 32)       { layer = 0; rate = 1; j = 0;              g = bid; }
  else if (bid < 96)  { layer = 1; rate = 2; j = (bid-32)  >> 5; g = (bid-32)  & 31; }
  else if (bid < 224) { layer = 2; rate = 4; j = (bid-96)  >> 5; g = (bid-96)  & 31; }
  else                { layer = 3; rate = 8; j = (bid-224) >> 5; g = (bid-224) & 31; }

  ushort* h3 = h1;  // alias safe: h1[t]'s only reader (L2 phase t&1) consumes
                    // it before h2[t] is published, which gates L3's write.
  const ushort* xin = (layer == 0) ? xhat : (layer == 1) ? h1 : (layer == 2) ? h2 : h3;
  ushort* hout      = (layer == 0) ? h1   : (layer == 1) ? h2 : (layer == 2) ? h3 : h4;
  const float* Wih = (layer == 0) ? Wih0 : (Wih_rest + (size_t)(layer-1)*256*64);
  const float* Whh = Whh_all + (size_t)layer*256*64;
  const float* bih = bih_all + layer*256;
  const float* bhh = bhh_all + layer*256;

  if (layer == 0) lstm_scan<1>(xin, hout, Wih, Whh, bih, bhh, rate, j, g, layer, flags);
  else            lstm_scan<2>(xin, hout, Wih, Whh, bih, bhh, rate, j, g, layer, flags);
}

// ---------------- adapter: out1 = (h4+h2) @ adW.T + adb ----------------
__global__ __launch_bounds__(256) void adapter_kernel(const ushort* __restrict__ h4, const ushort* __restrict__ h2,
      const float* __restrict__ adW, const float* __restrict__ adb, float* __restrict__ out) {
  __shared__ __align__(16) float xrow[64*64];
  const int i = threadIdx.x;
  const int total = T_WIN*512;
  const int base = blockIdx.x * 64;
  for (int e = i; e < 64*64; e += 256) {
    int r = e >> 6;
    size_t gi = (size_t)(base + r)*64 + (e & 63);
    float v = 0.f;
    if (base + r < total) {
      __hip_bfloat16 a = *reinterpret_cast<const __hip_bfloat16*>(h4 + gi);
      __hip_bfloat16 b = *reinterpret_cast<const __hip_bfloat16*>(h2 + gi);
      v = __bfloat162float(a) + __bfloat162float(b);
    }
    xrow[e] = v;
  }
  const int o  = i & 31;
  const int rg = i >> 5;
  float w[64]; float bo = 0.f;
  if (o < 28) {
    #pragma unroll
    for (int uu=0;uu<64;++uu) w[uu] = adW[o*64+uu];
    bo = adb[o];
  }
  __syncthreads();
  if (o < 28) {
    #pragma unroll
    for (int rr=0; rr<8; ++rr) {
      int r = rg*8 + rr;
      if (base + r >= total) break;
      const float4* xp = (const float4*)(&xrow[r*64]);
      float a0 = bo, a1 = 0.f, a2 = 0.f, a3 = 0.f;
      #pragma unroll
      for (int q=0;q<16;++q) {
        float4 xv = xp[q];
        a0 += w[4*q+0]*xv.x; a1 += w[4*q+1]*xv.y;
        a2 += w[4*q+2]*xv.z; a3 += w[4*q+3]*xv.w;
      }
      out[(size_t)(base+r)*28 + o] = (a0+a1)+(a2+a3);
    }
  }
}

extern "C" void kernel_launch(void* const* d_in, const int* in_sizes, int n_in,
                              void* d_out, int out_size, void* d_ws, size_t ws_size,
                              hipStream_t stream) {
  const float* y         = (const float*)d_in[0];
  const int*   idxs      = (const int*)d_in[1];
  const float* noise     = (const float*)d_in[2];
  const float* lev_sms   = (const float*)d_in[3];
  const float* seas_sms  = (const float*)d_in[4];
  const float* init_seas = (const float*)d_in[5];
  const float* Wih0      = (const float*)d_in[6];
  const float* Wih_rest  = (const float*)d_in[7];
  const float* Whh_all   = (const float*)d_in[8];
  const float* bih_all   = (const float*)d_in[9];
  const float* bhh_all   = (const float*)d_in[10];
  const float* adW       = (const float*)d_in[11];
  const float* adb       = (const float*)d_in[12];

  const size_t NWIN28 = (size_t)T_WIN*512*28;
  const size_t NWIN64 = (size_t)T_WIN*512*64;
  float* out_wy   = (float*)d_out;
  float* out_yhat = out_wy + NWIN28;
  float* out_lev  = out_yhat + NWIN28;

  int*   flags = (int*)d_ws;                       // 4 KiB reserved
  float* seas  = (float*)((char*)d_ws + 4096);
  float* lnorm = seas  + (size_t)NSER*NTIME;
  float* llev  = lnorm + (size_t)NSER*NTIME;
  ushort* xhat = (ushort*)(llev + (size_t)NSER*NTIME);
  ushort* h1   = (ushort*)((char*)xhat + NWIN28*2);
  ushort* h2   = (ushort*)((char*)h1 + NWIN64*2);
  ushort* h4   = (ushort*)((char*)h2 + NWIN64*2);

  size_t need = 4096 + (size_t)3*NSER*NTIME*4 + NWIN28*2 + 3*NWIN64*2;
  if (ws_size < need) {
    fprintf(stderr, "kernel_launch: ws_size %zu < needed %zu\n", ws_size, need);
    return;
  }

  hipMemsetAsync(flags, 0, FLAGS_INTS*sizeof(int), stream);
  es_kernel<<<2,256,0,stream>>>(y, idxs, lev_sms, seas_sms, init_seas, out_lev, seas);
  lnorm_kernel<<<(NSER*NTIME)/256,256,0,stream>>>(y, seas, out_lev, lnorm, llev);
  window_kernel<<<NWIN28/256,256,0,stream>>>(lnorm, llev, noise, out_wy, xhat);

  lstm_fused<<<480,256,0,stream>>>(xhat, h1, h2, h4, Wih0, Wih_rest, Whh_all,
                                   bih_all, bhh_all, flags);

  adapter_kernel<<<(T_WIN*512)/64,256,0,stream>>>(h4, h2, adW, adb, out_yhat);
}

// Round 7
// 3936.834 us; speedup vs baseline: 3.0178x; 1.0072x over previous
//
#include <hip/hip_runtime.h>
#include <hip/hip_bf16.h>
#include <cstdio>

typedef __hip_bfloat16 bf16;
typedef __attribute__((ext_vector_type(8))) short short8v;
typedef __attribute__((ext_vector_type(4))) float f32x4;

#define T_WIN 1993      // N_WINDOWS
#define NSER 512
#define NTIME 2048
#define NGRP 32
#define FLAGS_INTS (4*8*NGRP)

__device__ __forceinline__ float sigmf(float x) { return __fdividef(1.f, 1.f + __expf(-x)); }
__device__ __forceinline__ float tanhf_fast(float x) { return 1.f - __fdividef(2.f, __expf(2.f*x) + 1.f); }
__device__ __forceinline__ ushort f2bfu(float f) {
  __hip_bfloat16 h = __float2bfloat16(f);
  return *reinterpret_cast<ushort*>(&h);
}

// ---------------- ES scan: 1 thread per series ----------------
__global__ void es_kernel(const float* __restrict__ y, const int* __restrict__ idxs,
                          const float* __restrict__ lev_sms, const float* __restrict__ seas_sms,
                          const float* __restrict__ init_seas,
                          float* __restrict__ levels, float* __restrict__ seas) {
  int s = blockIdx.x*blockDim.x + threadIdx.x;
  if (s >= NSER) return;
  int id = idxs[s];
  float ls = sigmf(lev_sms[id]);
  float ss = sigmf(seas_sms[id]);
  float buf[8];
  #pragma unroll
  for (int k=0;k<7;++k) buf[k] = __expf(init_seas[id*7+k]);
  buf[7] = buf[0];
  const float* yr = y + (size_t)s*NTIME;
  float* lr = levels + (size_t)s*NTIME;
  float* sr = seas + (size_t)s*NTIME;
  float lev = __fdividef(yr[0], buf[0]);
  lr[0] = lev;
  #pragma unroll
  for (int t=0;t<8;++t) sr[t] = buf[t];
  #pragma unroll 8
  for (int t=1;t<NTIME;++t) {
    float yt = yr[t];
    float st = buf[1];
    lev = ls*__fdividef(yt,st) + (1.f-ls)*lev;
    float ns = ss*__fdividef(yt,lev) + (1.f-ss)*st;
    #pragma unroll
    for (int k=0;k<7;++k) buf[k] = buf[k+1];
    buf[7] = ns;
    lr[t] = lev;
    if (t+7 < NTIME) sr[t+7] = ns;
  }
}

// ---------------- log(norm), log(levels) ----------------
__global__ void lnorm_kernel(const float* __restrict__ y, const float* __restrict__ seas,
                             const float* __restrict__ levels,
                             float* __restrict__ lnorm, float* __restrict__ llev) {
  int i = blockIdx.x*256 + threadIdx.x;
  lnorm[i] = __logf(__fdividef(y[i], seas[i]));
  llev[i]  = __logf(levels[i]);
}

// ---------------- windows: windows_y (out0) + RNN input xhat ----------------
__global__ void window_kernel(const float* __restrict__ lnorm, const float* __restrict__ llev,
                              const float* __restrict__ noise,
                              float* __restrict__ wy, ushort* __restrict__ xhat) {
  int idx = blockIdx.x*256 + threadIdx.x;   // (w*512 + s)*28 + k
  int k  = idx % 28;
  int rs = idx / 28;
  int s  = rs & 511;
  int w  = rs >> 9;
  float lv = llev[s*NTIME + 28 + w];
  const float* Ln = lnorm + s*NTIME;
  wy[idx]   = Ln[w+28+k] - lv;
  xhat[idx] = f2bfu(Ln[w+k] - lv + 0.001f*noise[idx]);
}

// ---------------- fused 4-layer pipelined LSTM scan ----------------
// Per block: 16 series, one (layer, phase). Wave w owns units [16w,16w+16),
// all 4 gates. Steady state is BRANCH-FREE 8-step chunks so the compiler
// keeps exact (counted) vmcnt for the 2-step-ahead x prefetch. Flag waits
// and progress publishes live only at chunk boundaries.
// DEADLOCK FIX (r6): `need` is clamped to the producer's TERMINAL flag
// prodmax = (T_WIN-1-pp0)/SRCR + 1. Clamped (dummy) prefetch times map to
// producer phase 0's timeline, whose step count can exceed phase pp0's by 1
// — the unclamped wait was unsatisfiable for pp0 != 0 (r6 hang). Dummy
// prefetch values are never consumed, so a bounded wait is sufficient.
template<int KXS, int LAYER>
__device__ __forceinline__ void lstm_scan(
    const ushort* __restrict__ xin, ushort* __restrict__ hout,
    const float* __restrict__ Wih, const float* __restrict__ Whh,
    const float* __restrict__ bih, const float* __restrict__ bhh,
    const int j, const int g, int* __restrict__ flags)
{
  constexpr int KST  = KXS + 2;
  constexpr int D    = (KXS == 1) ? 28 : 64;
  constexpr int KX   = KXS * 32;
  constexpr int RATE = 1 << LAYER;
  constexpr int SRCR = (LAYER > 0) ? (RATE >> 1) : 1;

  __shared__ __align__(16) ushort hbuf[2][16*72];

  const int i    = threadIdx.x;
  const int lane = i & 63;
  const int wid  = i >> 6;
  const int n15  = lane & 15;
  const int kq   = lane >> 4;
  const int base = g * 16;
  const int wm   = i >> 4;
  const int wu   = (i & 15) * 4;
  const uint km  = (kq == 3) ? 0u : ~0u;   // branchless D=28 K-pad mask

  // ---- weight B-fragments (permuted rows: gate gg, unit 16*wid+n15) ----
  short8v wfrag[4][KST];
  float bias[4];
  #pragma unroll
  for (int gg = 0; gg < 4; ++gg) {
    const int R = gg*64 + wid*16 + n15;
    bias[gg] = bih[R] + bhh[R];
    #pragma unroll
    for (int kk = 0; kk < KST; ++kk) {
      #pragma unroll
      for (int jj = 0; jj < 8; ++jj) {
        const int k = kk*32 + kq*8 + jj;
        float v;
        if (k < KX) v = (k < D) ? Wih[R*D + k] : 0.f;
        else        v = Whh[R*64 + (k - KX)];
        wfrag[gg][kk][jj] = (short)f2bfu(v);
      }
    }
  }

  for (int e = i; e < 1152; e += 256) hbuf[0][e] = 0;
  __syncthreads();

  const int nsteps = (T_WIN - 1 - j)/RATE + 1;
  const int u = wid*16 + n15;
  float cc[4] = {0.f, 0.f, 0.f, 0.f};

  int* myflag = &flags[(LAYER*8 + j)*NGRP + g];
  int* fp = nullptr;
  int seen0 = 0;
  int prodmax = 0x7fffffff;
  if constexpr (LAYER > 0) {
    const int pp0 = j % SRCR;
    fp = &flags[((LAYER-1)*8 + pp0)*NGRP + g];
    prodmax = (T_WIN - 1 - pp0)/SRCR + 1;   // producer's terminal flag value
  }

  auto wait_for = [&](int t) __attribute__((always_inline)) {
    if constexpr (LAYER > 0) {
      const int tc = (t < T_WIN) ? t : (T_WIN - 1);
      int need = tc/SRCR + 1;
      need = (need < prodmax) ? need : prodmax;   // liveness clamp (r6 fix)
      if (seen0 >= need) return;
      while (__hip_atomic_load(fp, __ATOMIC_RELAXED, __HIP_MEMORY_SCOPE_AGENT) < need)
        __builtin_amdgcn_s_sleep(8);
      seen0 = __hip_atomic_load(fp, __ATOMIC_ACQUIRE, __HIP_MEMORY_SCOPE_AGENT);
    }
  };

  auto loadx = [&](int t, short8v* xf) __attribute__((always_inline)) {
    const int tc = (t < T_WIN) ? t : (T_WIN - 1);
    const ushort* p = xin + ((size_t)tc*512 + base + n15)*(size_t)D + kq*8;
    if constexpr (D == 64) {
      xf[0] = *reinterpret_cast<const short8v*>(p);
      xf[1] = *reinterpret_cast<const short8v*>(p + 32);
    } else {
      ushort4 a = *reinterpret_cast<const ushort4*>(p);
      ushort4 b = *reinterpret_cast<const ushort4*>(p + 4);   // cols 28..31
      short8v r;
      r[0]=(short)a.x; r[1]=(short)a.y; r[2]=(short)a.z; r[3]=(short)a.w;
      r[4]=(short)(ushort)(b.x & km); r[5]=(short)(ushort)(b.y & km);
      r[6]=(short)(ushort)(b.z & km); r[7]=(short)(ushort)(b.w & km);
      xf[0] = r;
    }
  };

  // one recurrence step; xf was loaded 2 steps ago; reloads xf for S+2.
  // wb is a LITERAL at every call site -> folds, no branch in chunk body.
  auto step = [&](int S, short8v* xf, bool wb) __attribute__((always_inline)) {
    const int p_ = S & 1;
    const int t_ = j + S*RATE;
    short8v hf0 = *reinterpret_cast<const short8v*>(&hbuf[p_][n15*72 + kq*8]);
    short8v hf1 = *reinterpret_cast<const short8v*>(&hbuf[p_][n15*72 + 32 + kq*8]);
    if (wb) {  // lagged coalesced writeback of h_{S-1}
      uint2 hv = *reinterpret_cast<const uint2*>(&hbuf[p_][wm*72 + wu]);
      *reinterpret_cast<uint2*>(&hout[((size_t)(t_ - RATE)*512 + base + wm)*64 + wu]) = hv;
    }
    f32x4 acc0 = {bias[0], bias[0], bias[0], bias[0]};
    f32x4 acc1 = {bias[1], bias[1], bias[1], bias[1]};
    f32x4 acc2 = {bias[2], bias[2], bias[2], bias[2]};
    f32x4 acc3 = {bias[3], bias[3], bias[3], bias[3]};
    #pragma unroll
    for (int kk = 0; kk < KXS; ++kk) {
      acc0 = __builtin_amdgcn_mfma_f32_16x16x32_bf16(xf[kk], wfrag[0][kk], acc0, 0, 0, 0);
      acc1 = __builtin_amdgcn_mfma_f32_16x16x32_bf16(xf[kk], wfrag[1][kk], acc1, 0, 0, 0);
      acc2 = __builtin_amdgcn_mfma_f32_16x16x32_bf16(xf[kk], wfrag[2][kk], acc2, 0, 0, 0);
      acc3 = __builtin_amdgcn_mfma_f32_16x16x32_bf16(xf[kk], wfrag[3][kk], acc3, 0, 0, 0);
    }
    acc0 = __builtin_amdgcn_mfma_f32_16x16x32_bf16(hf0, wfrag[0][KXS], acc0, 0, 0, 0);
    acc1 = __builtin_amdgcn_mfma_f32_16x16x32_bf16(hf0, wfrag[1][KXS], acc1, 0, 0, 0);
    acc2 = __builtin_amdgcn_mfma_f32_16x16x32_bf16(hf0, wfrag[2][KXS], acc2, 0, 0, 0);
    acc3 = __builtin_amdgcn_mfma_f32_16x16x32_bf16(hf0, wfrag[3][KXS], acc3, 0, 0, 0);
    acc0 = __builtin_amdgcn_mfma_f32_16x16x32_bf16(hf1, wfrag[0][KXS+1], acc0, 0, 0, 0);
    acc1 = __builtin_amdgcn_mfma_f32_16x16x32_bf16(hf1, wfrag[1][KXS+1], acc1, 0, 0, 0);
    acc2 = __builtin_amdgcn_mfma_f32_16x16x32_bf16(hf1, wfrag[2][KXS+1], acc2, 0, 0, 0);
    acc3 = __builtin_amdgcn_mfma_f32_16x16x32_bf16(hf1, wfrag[3][KXS+1], acc3, 0, 0, 0);
    loadx(t_ + 2*RATE, xf);   // prefetch for S+2 into the just-consumed regs
    #pragma unroll
    for (int r = 0; r < 4; ++r) {
      const float zi = acc0[r], zf = acc1[r], zg = acc2[r], zo = acc3[r];
      cc[r] = sigmf(zf)*cc[r] + sigmf(zi)*tanhf_fast(zg);
      const float h_ = sigmf(zo)*tanhf_fast(cc[r]);
      hbuf[p_^1][(kq*4 + r)*72 + u] = f2bfu(h_);
    }
    __builtin_amdgcn_sched_barrier(0);
    asm volatile("s_waitcnt lgkmcnt(0)");
    __builtin_amdgcn_sched_barrier(0);
    __builtin_amdgcn_s_barrier();
  };

  short8v xfA[KXS], xfB[KXS];
  wait_for(j + 2*RATE);                 // covers prologue + step0's prefetch
  loadx(j, xfA);
  loadx(j + RATE, xfB);
  step(0, xfA, false);

  int S = 1;
  for (; S + 8 <= nsteps; S += 8) {
    wait_for(j + (S + 9)*RATE);         // covers all prefetches in this chunk
    step(S+0, xfB, true);
    step(S+1, xfA, true);
    step(S+2, xfB, true);
    step(S+3, xfA, true);
    step(S+4, xfB, true);
    step(S+5, xfA, true);
    step(S+6, xfB, true);
    step(S+7, xfA, true);
    if constexpr (LAYER < 3) {          // publish: h stored for steps < S+7
      asm volatile("s_waitcnt vmcnt(0)");
      __builtin_amdgcn_s_barrier();
      if (i == 0)
        __hip_atomic_store(myflag, S+7, __ATOMIC_RELEASE, __HIP_MEMORY_SCOPE_AGENT);
    }
  }
  for (; S < nsteps; ++S) {             // tail (<8 steps, branches ok)
    wait_for(j + (S + 2)*RATE);
    if (S & 1) step(S, xfB, true);
    else       step(S, xfA, true);
  }

  // final h writeback + terminal publish
  {
    const int pF = nsteps & 1;
    const int tF = j + (nsteps - 1)*RATE;
    uint2 hv = *reinterpret_cast<const uint2*>(&hbuf[pF][wm*72 + wu]);
    *reinterpret_cast<uint2*>(&hout[((size_t)tF*512 + base + wm)*64 + wu]) = hv;
  }
  if constexpr (LAYER < 3) {
    asm volatile("s_waitcnt vmcnt(0)");
    __builtin_amdgcn_s_barrier();
    if (i == 0)
      __hip_atomic_store(myflag, nsteps, __ATOMIC_RELEASE, __HIP_MEMORY_SCOPE_AGENT);
  }
}

__global__ __launch_bounds__(256, 2)
void lstm_fused(const ushort* __restrict__ xhat,
                ushort* __restrict__ h1, ushort* __restrict__ h2, ushort* __restrict__ h4,
                const float* __restrict__ Wih0, const float* __restrict__ Wih_rest,
                const float* __restrict__ Whh_all,
                const float* __restrict__ bih_all, const float* __restrict__ bhh_all,
                int* __restrict__ flags)
{
  const int bid = blockIdx.x;
  ushort* h3 = h1;  // alias safe: h1[t]'s only reader (L2 phase t&1) consumes
                    // it before h2[t] is published, which gates L3's write.
  if (bid < 32) {
    lstm_scan<1,0>(xhat, h1, Wih0, Whh_all, bih_all, bhh_all,
                   0, bid, flags);
  } else if (bid < 96) {
    lstm_scan<2,1>(h1, h2, Wih_rest, Whh_all + 256*64, bih_all + 256, bhh_all + 256,
                   (bid-32) >> 5, (bid-32) & 31, flags);
  } else if (bid < 224) {
    lstm_scan<2,2>(h2, h3, Wih_rest + 256*64, Whh_all + 2*256*64, bih_all + 2*256, bhh_all + 2*256,
                   (bid-96) >> 5, (bid-96) & 31, flags);
  } else {
    lstm_scan<2,3>(h3, h4, Wih_rest + 2*256*64, Whh_all + 3*256*64, bih_all + 3*256, bhh_all + 3*256,
                   (bid-224) >> 5, (bid-224) & 31, flags);
  }
}

// ---------------- adapter: out1 = (h4+h2) @ adW.T + adb ----------------
__global__ __launch_bounds__(256) void adapter_kernel(const ushort* __restrict__ h4, const ushort* __restrict__ h2,
      const float* __restrict__ adW, const float* __restrict__ adb, float* __restrict__ out) {
  __shared__ __align__(16) float xrow[64*64];
  const int i = threadIdx.x;
  const int total = T_WIN*512;
  const int base = blockIdx.x * 64;
  for (int e = i; e < 64*64; e += 256) {
    int r = e >> 6;
    size_t gi = (size_t)(base + r)*64 + (e & 63);
    float v = 0.f;
    if (base + r < total) {
      __hip_bfloat16 a = *reinterpret_cast<const __hip_bfloat16*>(h4 + gi);
      __hip_bfloat16 b = *reinterpret_cast<const __hip_bfloat16*>(h2 + gi);
      v = __bfloat162float(a) + __bfloat162float(b);
    }
    xrow[e] = v;
  }
  const int o  = i & 31;
  const int rg = i >> 5;
  float w[64]; float bo = 0.f;
  if (o < 28) {
    #pragma unroll
    for (int uu=0;uu<64;++uu) w[uu] = adW[o*64+uu];
    bo = adb[o];
  }
  __syncthreads();
  if (o < 28) {
    #pragma unroll
    for (int rr=0; rr<8; ++rr) {
      int r = rg*8 + rr;
      if (base + r >= total) break;
      const float4* xp = (const float4*)(&xrow[r*64]);
      float a0 = bo, a1 = 0.f, a2 = 0.f, a3 = 0.f;
      #pragma unroll
      for (int q=0;q<16;++q) {
        float4 xv = xp[q];
        a0 += w[4*q+0]*xv.x; a1 += w[4*q+1]*xv.y;
        a2 += w[4*q+2]*xv.z; a3 += w[4*q+3]*xv.w;
      }
      out[(size_t)(base+r)*28 + o] = (a0+a1)+(a2+a3);
    }
  }
}

extern "C" void kernel_launch(void* const* d_in, const int* in_sizes, int n_in,
                              void* d_out, int out_size, void* d_ws, size_t ws_size,
                              hipStream_t stream) {
  const float* y         = (const float*)d_in[0];
  const int*   idxs      = (const int*)d_in[1];
  const float* noise     = (const float*)d_in[2];
  const float* lev_sms   = (const float*)d_in[3];
  const float* seas_sms  = (const float*)d_in[4];
  const float* init_seas = (const float*)d_in[5];
  const float* Wih0      = (const float*)d_in[6];
  const float* Wih_rest  = (const float*)d_in[7];
  const float* Whh_all   = (const float*)d_in[8];
  const float* bih_all   = (const float*)d_in[9];
  const float* bhh_all   = (const float*)d_in[10];
  const float* adW       = (const float*)d_in[11];
  const float* adb       = (const float*)d_in[12];

  const size_t NWIN28 = (size_t)T_WIN*512*28;
  const size_t NWIN64 = (size_t)T_WIN*512*64;
  float* out_wy   = (float*)d_out;
  float* out_yhat = out_wy + NWIN28;
  float* out_lev  = out_yhat + NWIN28;

  int*   flags = (int*)d_ws;                       // 4 KiB reserved
  float* seas  = (float*)((char*)d_ws + 4096);
  float* lnorm = seas  + (size_t)NSER*NTIME;
  float* llev  = lnorm + (size_t)NSER*NTIME;
  ushort* xhat = (ushort*)(llev + (size_t)NSER*NTIME);
  ushort* h1   = (ushort*)((char*)xhat + NWIN28*2);
  ushort* h2   = (ushort*)((char*)h1 + NWIN64*2);
  ushort* h4   = (ushort*)((char*)h2 + NWIN64*2);

  size_t need = 4096 + (size_t)3*NSER*NTIME*4 + NWIN28*2 + 3*NWIN64*2;
  if (ws_size < need) {
    fprintf(stderr, "kernel_launch: ws_size %zu < needed %zu\n", ws_size, need);
    return;
  }

  hipMemsetAsync(flags, 0, FLAGS_INTS*sizeof(int), stream);
  es_kernel<<<2,256,0,stream>>>(y, idxs, lev_sms, seas_sms, init_seas, out_lev, seas);
  lnorm_kernel<<<(NSER*NTIME)/256,256,0,stream>>>(y, seas, out_lev, lnorm, llev);
  window_kernel<<<NWIN28/256,256,0,stream>>>(lnorm, llev, noise, out_wy, xhat);

  lstm_fused<<<480,256,0,stream>>>(xhat, h1, h2, h4, Wih0, Wih_rest, Whh_all,
                                   bih_all, bhh_all, flags);

  adapter_kernel<<<(T_WIN*512)/64,256,0,stream>>>(h4, h2, adW, adb, out_yhat);
}